// Round 3
// baseline (712.546 us; speedup 1.0000x reference)
//
#include <hip/hip_runtime.h>
#include <math.h>

#define Bb 64
#define Nn 1000
#define Gg 500
#define Hh 256
#define GP 512
#define NP 1024

// float-offset workspace layout (total 41,746,432 floats = 167 MB)
#define WS_MP   0u
#define WS_QG   16384u
#define WS_RS   32768u
#define WS_WCH  65536u
#define WS_WCL  131072u
#define WS_EH   196608u     // emb hi  bf16 [B][N][H]
#define WS_EL   8388608u    // emb lo  bf16 [B][N][H]
#define WS_TH   16580608u   // embT hi bf16 [B][H][NP]
#define WS_TL   24969216u   // embT lo bf16 [B][H][NP]
#define WS_PL   33357824u   // pooled fp32 [B][GP][H]
#define WS_FQ   WS_TH       // fq fp32 [B][GP][H] overlays embT (dead after k_pool)

typedef __attribute__((ext_vector_type(8))) short bf16x8;
typedef __attribute__((ext_vector_type(8))) short short8;
typedef __attribute__((ext_vector_type(4))) float f32x4;

#define MFMA(a,b,c) __builtin_amdgcn_mfma_f32_16x16x32_bf16(a,b,c,0,0,0)

__device__ __forceinline__ float tanh10(float s) {
  float a = fabsf(s);
  float e = __expf(-2.0f * a);
  float t = (1.0f - e) / (1.0f + e);
  return copysignf(10.0f * t, s);
}

__device__ __forceinline__ void load8(const float* __restrict__ p, float x[8]) {
  float4 a = ((const float4*)p)[0];
  float4 b = ((const float4*)p)[1];
  x[0]=a.x; x[1]=a.y; x[2]=a.z; x[3]=a.w; x[4]=b.x; x[5]=b.y; x[6]=b.z; x[7]=b.w;
}

__device__ __forceinline__ void split1(float v, unsigned short& hi, unsigned short& lo) {
  unsigned bits = __float_as_uint(v);
  hi = (unsigned short)(bits >> 16);
  float hf = __uint_as_float(bits & 0xFFFF0000u);
  lo = (unsigned short)(__float_as_uint(v - hf) >> 16);
}

__device__ __forceinline__ void cvt_split(const float x[8], bf16x8& hi, bf16x8& lo) {
#pragma unroll
  for (int i = 0; i < 8; ++i) {
    unsigned bits = __float_as_uint(x[i]);
    hi[i] = (short)(bits >> 16);
    float hf = __uint_as_float(bits & 0xFFFF0000u);
    lo[i] = (short)(__float_as_uint(x[i] - hf) >> 16);
  }
}

// ---------------- zero mp+qg+rs: grid(256), block(256) ----------------
__global__ __launch_bounds__(256) void k_zero(float* __restrict__ ws) {
  ws[blockIdx.x * 256 + threadIdx.x] = 0.f;
}

// ---------------- prep: emb -> bf16 hi/lo + transposed bf16 + mean partials ----
// grid(nt=16, ht=4, b=64), block(256)
__global__ __launch_bounds__(256) void k_prep(const float* __restrict__ emb,
                                              float* __restrict__ ws) {
  __shared__ float tile[64][65];
  __shared__ float csumL[256];
  int nt = blockIdx.x, ht = blockIdx.y, b = blockIdx.z;
  int t = threadIdx.x, c = t & 63, w = t >> 6;
  int n0 = nt * 64, h0 = ht * 64;
  unsigned short* eh = (unsigned short*)(ws + WS_EH);
  unsigned short* el = (unsigned short*)(ws + WS_EL);
  unsigned short* th = (unsigned short*)(ws + WS_TH);
  unsigned short* tl = (unsigned short*)(ws + WS_TL);
  float csum = 0.f;
#pragma unroll
  for (int rr = 0; rr < 16; ++rr) {
    int r = w * 16 + rr;
    int n = n0 + r;
    float v = 0.f;
    if (n < Nn) {
      size_t idx = ((size_t)(b * Nn + n)) * Hh + h0 + c;
      v = emb[idx];
      unsigned short hi, lo;
      split1(v, hi, lo);
      eh[idx] = hi; el[idx] = lo;
    }
    tile[r][c] = v;
    csum += v;
  }
  __syncthreads();
  {
    int h_l = t >> 2, nseg = t & 3;
    short8 h8a, h8b, l8a, l8b;
#pragma unroll
    for (int i = 0; i < 16; ++i) {
      float v = tile[nseg * 16 + i][h_l];
      unsigned short hi, lo;
      split1(v, hi, lo);
      if (i < 8) { h8a[i] = (short)hi; l8a[i] = (short)lo; }
      else       { h8b[i-8] = (short)hi; l8b[i-8] = (short)lo; }
    }
    size_t base = ((size_t)(b * Hh + h0 + h_l)) * NP + n0 + nseg * 16;
    *(short8*)(th + base) = h8a; *(short8*)(th + base + 8) = h8b;
    *(short8*)(tl + base) = l8a; *(short8*)(tl + base + 8) = l8b;
  }
  __syncthreads();
  csumL[t] = csum;
  __syncthreads();
  if (t < 64) {
    float s = csumL[t] + csumL[t+64] + csumL[t+128] + csumL[t+192];
    atomicAdd(ws + WS_MP + b * Hh + h0 + t, s);
  }
}

// ---------------- q_graph: grid(B), block(256) ----------------
__global__ __launch_bounds__(256) void k_qgraph(const float* __restrict__ Wg,
                                                float* __restrict__ ws) {
  __shared__ float mean[Hh];
  int b = blockIdx.x, t = threadIdx.x;
  mean[t] = ws[WS_MP + b*Hh + t] * (1.0f/Nn);
  __syncthreads();
  const float4* wrow = (const float4*)(Wg + (size_t)t * Hh);
  float acc = 0.f;
#pragma unroll
  for (int h4 = 0; h4 < Hh/4; ++h4) {
    float4 w = wrow[h4];
    acc += mean[h4*4]*w.x + mean[h4*4+1]*w.y + mean[h4*4+2]*w.z + mean[h4*4+3]*w.w;
  }
  ws[WS_QG + b*Hh + t] = acc;
}

// ---------------- Wcat bf16 hi/lo: grid(256), block(256) ----------------
__global__ __launch_bounds__(256) void k_wcat(const float* __restrict__ Wf,
                                              const float* __restrict__ Wl,
                                              const float* __restrict__ Wv,
                                              float* __restrict__ ws) {
  int o = blockIdx.x, k = threadIdx.x;
  unsigned short* wh = (unsigned short*)(ws + WS_WCH);
  unsigned short* wl = (unsigned short*)(ws + WS_WCL);
  unsigned short hi, lo;
  float v0 = Wv[o*Hh + k];
  split1(v0, hi, lo);
  wh[o*512 + k] = hi; wl[o*512 + k] = lo;
  float v1 = Wl[o*Hh + k] + Wf[o*Hh + k];
  split1(v1, hi, lo);
  wh[o*512 + 256 + k] = hi; wl[o*512 + 256 + k] = lo;
}

// ---------------- pool MFMA: pooled[b][g][h] = (1/N) mask @ emb ----------------
// grid(ht=2, gt=4, b=64), block(256): tile 128h x 128g, wave 64x64, K=NP
__global__ __launch_bounds__(256) void k_pool(const float* __restrict__ gm,
                                              float* __restrict__ ws) {
  int ht = blockIdx.x, gt = blockIdx.y, b = blockIdx.z;
  int t = threadIdx.x, w = t >> 6, lane = t & 63;
  int wr = w >> 1, wc = w & 1, l15 = lane & 15, lk = lane >> 4;
  const unsigned short* th = (const unsigned short*)(ws + WS_TH);
  const unsigned short* tl = (const unsigned short*)(ws + WS_TL);
  float* pooled = ws + WS_PL;
  f32x4 acc[4][4] = {};
  int hbase = ht*128 + wr*64;
  int gbase = gt*128 + wc*64;
  int koff_l = lk * 8;
  size_t arow[4];
  const float* brow[4];
#pragma unroll
  for (int fm = 0; fm < 4; ++fm)
    arow[fm] = ((size_t)(b*Hh + hbase + fm*16 + l15)) * NP;
#pragma unroll
  for (int fn = 0; fn < 4; ++fn) {
    int g = gbase + fn*16 + l15; if (g > Gg-1) g = Gg-1;
    brow[fn] = gm + ((size_t)(b*Gg + g)) * Nn;
  }
  for (int k0 = 0; k0 < NP; k0 += 32) {
    bf16x8 ah[4], al[4], bm[4];
#pragma unroll
    for (int fm = 0; fm < 4; ++fm) {
      ah[fm] = *(const bf16x8*)(th + arow[fm] + k0 + koff_l);
      al[fm] = *(const bf16x8*)(tl + arow[fm] + k0 + koff_l);
    }
    int kb = k0 + koff_l; if (kb > Nn - 8) kb = Nn - 8;  // stay in-row; pad k's nullified by embT zeros
#pragma unroll
    for (int fn = 0; fn < 4; ++fn) {
      float x[8]; load8(brow[fn] + kb, x);
#pragma unroll
      for (int i = 0; i < 8; ++i) bm[fn][i] = (x[i] < -1e30f) ? (short)0x3F80 : (short)0;
    }
#pragma unroll
    for (int fm = 0; fm < 4; ++fm)
#pragma unroll
      for (int fn = 0; fn < 4; ++fn) {
        acc[fm][fn] = MFMA(ah[fm], bm[fn], acc[fm][fn]);
        acc[fm][fn] = MFMA(al[fm], bm[fn], acc[fm][fn]);
      }
  }
#pragma unroll
  for (int fm = 0; fm < 4; ++fm)
#pragma unroll
    for (int fn = 0; fn < 4; ++fn) {
      int g = gbase + fn*16 + l15;
      int h = hbase + fm*16 + lk*4;
      f32x4 v = acc[fm][fn];
      float4 o4 = {v[0]*(1.f/Nn), v[1]*(1.f/Nn), v[2]*(1.f/Nn), v[3]*(1.f/Nn)};
      *(float4*)(pooled + ((size_t)(b*GP + g)) * Hh + h) = o4;
    }
}

// ---------------- finalq MFMA: fq = [pooled|emb[L]] @ Wcat^T + qg ----------------
// grid(ot=2, gt=8, b=64), block(256): tile 64g x 128o, K=512
__global__ __launch_bounds__(256) void k_finalq(const int* __restrict__ last_node,
                                                float* __restrict__ ws) {
  __shared__ int lL[64];
  int ot = blockIdx.x, gt = blockIdx.y, b = blockIdx.z;
  int t = threadIdx.x, w = t >> 6, lane = t & 63;
  int wr = w >> 1, wc = w & 1, l15 = lane & 15, lk = lane >> 4;
  const float* pooled = ws + WS_PL;
  const unsigned short* eh = (const unsigned short*)(ws + WS_EH);
  const unsigned short* el = (const unsigned short*)(ws + WS_EL);
  const unsigned short* wch = (const unsigned short*)(ws + WS_WCH);
  const unsigned short* wcl = (const unsigned short*)(ws + WS_WCL);
  float* fq = ws + WS_FQ;
  if (t < 64) {
    int g = gt*64 + t;
    lL[t] = last_node[b*Gg + (g < Gg ? g : Gg-1)];
  }
  __syncthreads();
  f32x4 acc[2][4] = {};
  int ocol0 = ot*128 + wc*64;
  int gA = gt*64 + wr*32;
  int Lrow[2];
  Lrow[0] = lL[wr*32 + l15];
  Lrow[1] = lL[wr*32 + 16 + l15];
  for (int k0 = 0; k0 < 512; k0 += 32) {
    bf16x8 ahi[2], alo[2], bhi[4], blo[4];
    if (k0 < 256) {
#pragma unroll
      for (int fm = 0; fm < 2; ++fm) {
        float x[8];
        load8(pooled + ((size_t)(b*GP + gA + fm*16 + l15)) * Hh + k0 + lk*8, x);
        cvt_split(x, ahi[fm], alo[fm]);
      }
    } else {
#pragma unroll
      for (int fm = 0; fm < 2; ++fm) {
        size_t base = ((size_t)(b*Nn + Lrow[fm])) * Hh + (k0 - 256) + lk*8;
        ahi[fm] = *(const bf16x8*)(eh + base);
        alo[fm] = *(const bf16x8*)(el + base);
      }
    }
#pragma unroll
    for (int fn = 0; fn < 4; ++fn) {
      size_t base = ((size_t)(ocol0 + fn*16 + l15)) * 512 + k0 + lk*8;
      bhi[fn] = *(const bf16x8*)(wch + base);
      blo[fn] = *(const bf16x8*)(wcl + base);
    }
#pragma unroll
    for (int fm = 0; fm < 2; ++fm)
#pragma unroll
      for (int fn = 0; fn < 4; ++fn) {
        acc[fm][fn] = MFMA(ahi[fm], bhi[fn], acc[fm][fn]);
        acc[fm][fn] = MFMA(ahi[fm], blo[fn], acc[fm][fn]);
        acc[fm][fn] = MFMA(alo[fm], bhi[fn], acc[fm][fn]);
      }
  }
  float qv[4];
#pragma unroll
  for (int fn = 0; fn < 4; ++fn) qv[fn] = ws[WS_QG + b*Hh + ocol0 + fn*16 + l15];
#pragma unroll
  for (int fm = 0; fm < 2; ++fm)
#pragma unroll
    for (int j = 0; j < 4; ++j) {
      int g = gt*64 + wr*32 + fm*16 + lk*4 + j;
#pragma unroll
      for (int fn = 0; fn < 4; ++fn)
        fq[((size_t)(b*GP + g)) * Hh + ocol0 + fn*16 + l15] = acc[fm][fn][j] + qv[fn];
    }
}

// ---------------- score MFMA + LDS-remapped vector epilogue ----------------
// grid(nt=8, gt=8, b=64), block(256): tile 64g x 128n
__global__ __launch_bounds__(256) void k_score(const float* __restrict__ dists,
                                               const int* __restrict__ last_node,
                                               const float* __restrict__ gm,
                                               float* __restrict__ ws,
                                               float* __restrict__ out) {
  __shared__ float sc[64 * 129];
  __shared__ int lL[64];
  __shared__ float lRs[256];
  int nt = blockIdx.x, gt = blockIdx.y, b = blockIdx.z;
  int t = threadIdx.x, w = t >> 6, lane = t & 63;
  int wr = w >> 1, wc = w & 1, l15 = lane & 15, lk = lane >> 4;
  const float* fq = ws + WS_FQ;
  const unsigned short* eh = (const unsigned short*)(ws + WS_EH);
  const unsigned short* el = (const unsigned short*)(ws + WS_EL);
  float* rs = ws + WS_RS;
  if (t < 64) {
    int g = gt*64 + t;
    lL[t] = last_node[b*Gg + (g < Gg ? g : Gg-1)];
  }
  __syncthreads();
  f32x4 acc[2][4] = {};
  int gA = gt*64 + wr*32;
  int ncol0 = nt*128 + wc*64;
  size_t brow[4];
#pragma unroll
  for (int fn = 0; fn < 4; ++fn) {
    int n = ncol0 + fn*16 + l15; if (n > Nn-1) n = Nn-1;
    brow[fn] = ((size_t)(b*Nn + n)) * Hh;
  }
  for (int k0 = 0; k0 < 256; k0 += 32) {
    bf16x8 ahi[2], alo[2], bhi[4], blo[4];
#pragma unroll
    for (int fm = 0; fm < 2; ++fm) {
      float x[8];
      load8(fq + ((size_t)(b*GP + gA + fm*16 + l15)) * Hh + k0 + lk*8, x);
      cvt_split(x, ahi[fm], alo[fm]);
    }
#pragma unroll
    for (int fn = 0; fn < 4; ++fn) {
      bhi[fn] = *(const bf16x8*)(eh + brow[fn] + k0 + lk*8);
      blo[fn] = *(const bf16x8*)(el + brow[fn] + k0 + lk*8);
    }
#pragma unroll
    for (int fm = 0; fm < 2; ++fm)
#pragma unroll
      for (int fn = 0; fn < 4; ++fn) {
        acc[fm][fn] = MFMA(ahi[fm], bhi[fn], acc[fm][fn]);
        acc[fm][fn] = MFMA(ahi[fm], blo[fn], acc[fm][fn]);
        acc[fm][fn] = MFMA(alo[fm], bhi[fn], acc[fm][fn]);
      }
  }
#pragma unroll
  for (int fm = 0; fm < 2; ++fm)
#pragma unroll
    for (int fn = 0; fn < 4; ++fn) {
      int n_l = wc*64 + fn*16 + l15;
#pragma unroll
      for (int j = 0; j < 4; ++j) {
        int g_l = wr*32 + fm*16 + lk*4 + j;
        sc[g_l * 129 + n_l] = acc[fm][fn][j] * 0.0625f;
      }
    }
  __syncthreads();
  // remapped vectorized epilogue: thread -> (g_l = t&63, seg = t>>6)
  int g_l = t & 63, seg = t >> 6;
  int g = gt*64 + g_l;
  float s = 0.f;
  if (g < Gg) {
    int L = lL[g_l];
    const float* drow = dists + ((size_t)(b*Nn + L)) * Nn;
    const float* grow = gm + ((size_t)(b*Gg + g)) * Nn;
    float* orow = out + ((size_t)(b*Gg + g)) * Nn;
#pragma unroll
    for (int i = 0; i < 8; ++i) {
      int n_l = seg*32 + i*4;
      int n = nt*128 + n_l;
      if (n < Nn) {
        float4 d4 = *(const float4*)(drow + n);
        float4 m4 = *(const float4*)(grow + n);
        const float c2 = 0.70710678118654752f;
        float4 p;
        p.x = (m4.x < -1e30f) ? 0.f : __expf(tanh10(sc[g_l*129 + n_l    ] - d4.x*c2) - 10.0f);
        p.y = (m4.y < -1e30f) ? 0.f : __expf(tanh10(sc[g_l*129 + n_l + 1] - d4.y*c2) - 10.0f);
        p.z = (m4.z < -1e30f) ? 0.f : __expf(tanh10(sc[g_l*129 + n_l + 2] - d4.z*c2) - 10.0f);
        p.w = (m4.w < -1e30f) ? 0.f : __expf(tanh10(sc[g_l*129 + n_l + 3] - d4.w*c2) - 10.0f);
        *(float4*)(orow + n) = p;
        s += p.x + p.y + p.z + p.w;
      }
    }
  }
  lRs[t] = s;
  __syncthreads();
  if (t < 64) {
    float tot = lRs[t] + lRs[t+64] + lRs[t+128] + lRs[t+192];
    int gg = gt*64 + t;
    if (gg < Gg) atomicAdd(rs + b*GP + gg, tot);
  }
}

// ---------------- normalize: out /= rowsum ----------------
__global__ __launch_bounds__(256) void k_norm(float* __restrict__ out,
                                              const float* __restrict__ ws) {
  int idx = blockIdx.x * 256 + threadIdx.x;  // float4 index
  int bg = idx / 250;                        // = b*Gg + g
  int b = bg / Gg, g = bg - b * Gg;
  float inv = 1.0f / ws[WS_RS + b*GP + g];
  float4* p = (float4*)out + idx;
  float4 v = *p;
  v.x *= inv; v.y *= inv; v.z *= inv; v.w *= inv;
  *p = v;
}

extern "C" void kernel_launch(void* const* d_in, const int* in_sizes, int n_in,
                              void* d_out, int out_size, void* d_ws, size_t ws_size,
                              hipStream_t stream) {
  const float* emb       = (const float*)d_in[0];
  const float* dists     = (const float*)d_in[1];
  const int*   last_node = (const int*)d_in[2];
  const float* gm        = (const float*)d_in[3];
  const float* Wg        = (const float*)d_in[4];
  const float* Wf        = (const float*)d_in[5];
  const float* Wl        = (const float*)d_in[6];
  const float* Wv        = (const float*)d_in[7];
  float* out = (float*)d_out;
  float* ws  = (float*)d_ws;

  hipLaunchKernelGGL(k_zero,   dim3(256),        dim3(256), 0, stream, ws);
  hipLaunchKernelGGL(k_prep,   dim3(16,4,Bb),    dim3(256), 0, stream, emb, ws);
  hipLaunchKernelGGL(k_qgraph, dim3(Bb),         dim3(256), 0, stream, Wg, ws);
  hipLaunchKernelGGL(k_wcat,   dim3(256),        dim3(256), 0, stream, Wf, Wl, Wv, ws);
  hipLaunchKernelGGL(k_pool,   dim3(2,4,Bb),     dim3(256), 0, stream, gm, ws);
  hipLaunchKernelGGL(k_finalq, dim3(2,8,Bb),     dim3(256), 0, stream, last_node, ws);
  hipLaunchKernelGGL(k_score,  dim3(8,8,Bb),     dim3(256), 0, stream, dists, last_node, gm, ws, out);
  hipLaunchKernelGGL(k_norm,   dim3(Bb*Gg*Nn/4/256), dim3(256), 0, stream, out, ws);
}

// Round 4
// 521.340 us; speedup vs baseline: 1.3668x; 1.3668x over previous
//
#include <hip/hip_runtime.h>
#include <hip/hip_fp16.h>
#include <math.h>

#define Bb 64
#define Nn 1000
#define Gg 500
#define Hh 256
#define GP 512
#define NP 1024

// float offsets into d_ws (total 42,762,240 floats = 171 MB)
#define WS_MP   0u           // [B][H] fp32 column sums (zeroed each launch)
#define WS_QG   16384u       // [B][H] fp32 q_graph
#define WS_BM   32768u       // u16 [B][GP][64]  visited bitmask (4 MB)
#define WS_WCH  1081344u     // u16 [256][512] Wcat hi
#define WS_WCL  1146880u     // u16 [256][512] Wcat lo
#define WS_EH   1212416u     // u16 [B][N][H] emb hi
#define WS_EL   9404416u     // u16 [B][N][H] emb lo
#define WS_TH   17596416u    // u16 [B][H][NP] embT hi (dead after k_pool)
#define WS_TL   25985024u    // u16 [B][H][NP] embT lo
#define WS_PH   34373632u    // u16 [B][GP][H] pooled hi
#define WS_PL2  38567936u    // u16 [B][GP][H] pooled lo
#define WS_FH   WS_TH        // u16 [B][GP][H] fq hi (overlays embT)
#define WS_FL   WS_TL        // u16 [B][GP][H] fq lo

typedef __attribute__((ext_vector_type(8))) short bf16x8;
typedef __attribute__((ext_vector_type(8))) short short8;
typedef __attribute__((ext_vector_type(4))) float f32x4;
typedef __attribute__((ext_vector_type(4))) unsigned short u16x4;

#define MFMA(a,b,c) __builtin_amdgcn_mfma_f32_16x16x32_bf16(a,b,c,0,0,0)

__device__ __forceinline__ float tanh10(float s) {
  float a = fabsf(s);
  float e = __expf(-2.0f * a);
  float t = (1.0f - e) / (1.0f + e);
  return copysignf(10.0f * t, s);
}

__device__ __forceinline__ void split1(float v, unsigned short& hi, unsigned short& lo) {
  unsigned bits = __float_as_uint(v);
  hi = (unsigned short)(bits >> 16);
  float hf = __uint_as_float(bits & 0xFFFF0000u);
  lo = (unsigned short)(__float_as_uint(v - hf) >> 16);
}

// ---------------- zero mp: grid(64), block(256) ----------------
__global__ __launch_bounds__(256) void k_zero(float* __restrict__ ws) {
  ws[WS_MP + blockIdx.x * 256 + threadIdx.x] = 0.f;
}

// ---------------- prep: emb -> eh/el + th/tl + column sums ----------------
// grid(nt=16, ht=4, b=64), block(256)
__global__ __launch_bounds__(256) void k_prep(const float* __restrict__ emb,
                                              float* __restrict__ ws) {
  __shared__ float tile[64][65];
  __shared__ float csumL[256];
  int nt = blockIdx.x, ht = blockIdx.y, b = blockIdx.z;
  int t = threadIdx.x, c = t & 63, w = t >> 6;
  int n0 = nt * 64, h0 = ht * 64;
  unsigned short* eh = (unsigned short*)(ws + WS_EH);
  unsigned short* el = (unsigned short*)(ws + WS_EL);
  unsigned short* th = (unsigned short*)(ws + WS_TH);
  unsigned short* tl = (unsigned short*)(ws + WS_TL);
  float csum = 0.f;
#pragma unroll
  for (int rr = 0; rr < 16; ++rr) {
    int r = w * 16 + rr;
    int n = n0 + r;
    float v = 0.f;
    if (n < Nn) {
      size_t idx = ((size_t)(b * Nn + n)) * Hh + h0 + c;
      v = emb[idx];
      unsigned short hi, lo;
      split1(v, hi, lo);
      eh[idx] = hi; el[idx] = lo;
    }
    tile[r][c] = v;
    csum += v;
  }
  __syncthreads();
  {
    int h_l = t >> 2, nseg = t & 3;
    short8 h8a, h8b, l8a, l8b;
#pragma unroll
    for (int i = 0; i < 16; ++i) {
      float v = tile[nseg * 16 + i][h_l];
      unsigned short hi, lo;
      split1(v, hi, lo);
      if (i < 8) { h8a[i] = (short)hi; l8a[i] = (short)lo; }
      else       { h8b[i-8] = (short)hi; l8b[i-8] = (short)lo; }
    }
    size_t base = ((size_t)(b * Hh + h0 + h_l)) * NP + n0 + nseg * 16;
    *(short8*)(th + base) = h8a; *(short8*)(th + base + 8) = h8b;
    *(short8*)(tl + base) = l8a; *(short8*)(tl + base + 8) = l8b;
  }
  __syncthreads();
  csumL[t] = csum;
  __syncthreads();
  if (t < 64) {
    float s = csumL[t] + csumL[t+64] + csumL[t+128] + csumL[t+192];
    atomicAdd(ws + WS_MP + b * Hh + h0 + t, s);
  }
}

// ---------------- q_graph: grid(B), block(256) ----------------
__global__ __launch_bounds__(256) void k_qgraph(const float* __restrict__ Wg,
                                                float* __restrict__ ws) {
  __shared__ float mean[Hh];
  int b = blockIdx.x, t = threadIdx.x;
  mean[t] = ws[WS_MP + b*Hh + t] * (1.0f/Nn);
  __syncthreads();
  const float4* wrow = (const float4*)(Wg + (size_t)t * Hh);
  float acc = 0.f;
#pragma unroll
  for (int h4 = 0; h4 < Hh/4; ++h4) {
    float4 w = wrow[h4];
    acc += mean[h4*4]*w.x + mean[h4*4+1]*w.y + mean[h4*4+2]*w.z + mean[h4*4+3]*w.w;
  }
  ws[WS_QG + b*Hh + t] = acc;
}

// ---------------- Wcat bf16 hi/lo: grid(256), block(256) ----------------
__global__ __launch_bounds__(256) void k_wcat(const float* __restrict__ Wf,
                                              const float* __restrict__ Wl,
                                              const float* __restrict__ Wv,
                                              float* __restrict__ ws) {
  int o = blockIdx.x, k = threadIdx.x;
  unsigned short* wh = (unsigned short*)(ws + WS_WCH);
  unsigned short* wl = (unsigned short*)(ws + WS_WCL);
  unsigned short hi, lo;
  float v0 = Wv[o*Hh + k];
  split1(v0, hi, lo);
  wh[o*512 + k] = hi; wl[o*512 + k] = lo;
  float v1 = Wl[o*Hh + k] + Wf[o*Hh + k];
  split1(v1, hi, lo);
  wh[o*512 + 256 + k] = hi; wl[o*512 + 256 + k] = lo;
}

// ---------------- bitmask: gm -> 1 bit per (b,g,n): grid(B*GP/4), block(256) ----
__global__ __launch_bounds__(256) void k_bm(const float* __restrict__ gm,
                                            float* __restrict__ ws) {
  int w = threadIdx.x >> 6, l = threadIdx.x & 63;
  int row = blockIdx.x * 4 + w;          // b*GP + g
  int b = row >> 9, g = row & 511;
  unsigned long long* dst = (unsigned long long*)((unsigned short*)(ws + WS_BM) + (size_t)row * 64);
  if (g < Gg) {
    const float* src = gm + ((size_t)b * Gg + g) * Nn;
#pragma unroll
    for (int i = 0; i < 16; ++i) {
      int n = i * 64 + l;
      bool bit = (n < Nn) ? (src[n] < -1e30f) : false;
      unsigned long long m = __ballot(bit);
      if (l == i) dst[i] = m;
    }
  } else {
    if (l < 16) dst[l] = 0ull;
  }
}

// ---------------- pool MFMA: pooled[g][h] = (1/N) mask @ emb, bf16 hi/lo out ----
// grid(ht=2, gt=4, b=64), block(256); A=embT(m=h), B=bitmask(n=g)
__global__ __launch_bounds__(256) void k_pool(float* __restrict__ ws) {
  int ht = blockIdx.x, gt = blockIdx.y, b = blockIdx.z;
  int t = threadIdx.x, w = t >> 6, lane = t & 63;
  int wr = w >> 1, wc = w & 1, l15 = lane & 15, lk = lane >> 4;
  const unsigned short* th = (const unsigned short*)(ws + WS_TH);
  const unsigned short* tl = (const unsigned short*)(ws + WS_TL);
  const unsigned short* bm = (const unsigned short*)(ws + WS_BM);
  unsigned short* ph = (unsigned short*)(ws + WS_PH);
  unsigned short* pl = (unsigned short*)(ws + WS_PL2);
  f32x4 acc[4][4] = {};
  int hbase = ht*128 + wr*64;
  int gbase = gt*128 + wc*64;
  size_t arow[4];
  const unsigned short* brow[4];
#pragma unroll
  for (int fm = 0; fm < 4; ++fm)
    arow[fm] = ((size_t)(b*Hh + hbase + fm*16 + l15)) * NP;
#pragma unroll
  for (int fn = 0; fn < 4; ++fn)
    brow[fn] = bm + ((size_t)(b*GP + gbase + fn*16 + l15)) * 64;
  int bitoff = (lk & 1) * 8;
  for (int k0 = 0; k0 < NP; k0 += 32) {
    bf16x8 ah[4], al[4], bmf[4];
#pragma unroll
    for (int fm = 0; fm < 4; ++fm) {
      ah[fm] = *(const bf16x8*)(th + arow[fm] + k0 + lk*8);
      al[fm] = *(const bf16x8*)(tl + arow[fm] + k0 + lk*8);
    }
#pragma unroll
    for (int fn = 0; fn < 4; ++fn) {
      unsigned c = brow[fn][(k0 >> 4) + (lk >> 1)];
#pragma unroll
      for (int i = 0; i < 8; ++i)
        bmf[fn][i] = ((c >> (bitoff + i)) & 1) ? (short)0x3F80 : (short)0;
    }
#pragma unroll
    for (int fm = 0; fm < 4; ++fm)
#pragma unroll
      for (int fn = 0; fn < 4; ++fn) {
        acc[fm][fn] = MFMA(ah[fm], bmf[fn], acc[fm][fn]);
        acc[fm][fn] = MFMA(al[fm], bmf[fn], acc[fm][fn]);
      }
  }
#pragma unroll
  for (int fm = 0; fm < 4; ++fm)
#pragma unroll
    for (int fn = 0; fn < 4; ++fn) {
      int g = gbase + fn*16 + l15;
      int h = hbase + fm*16 + lk*4;
      u16x4 vh, vl;
#pragma unroll
      for (int j = 0; j < 4; ++j) {
        unsigned short hi, lo;
        split1(acc[fm][fn][j] * (1.0f/Nn), hi, lo);
        vh[j] = hi; vl[j] = lo;
      }
      size_t idx = ((size_t)(b*GP + g)) * Hh + h;
      *(u16x4*)(ph + idx) = vh;
      *(u16x4*)(pl + idx) = vl;
    }
}

// ---------------- finalq MFMA (swapped): fq[g][o] = Wcat @ [pooled|emb[L]]^T + qg
// grid(ot=2, gt=4, b=64), block(256); A=Wcat(m=o), B=pooled/lastE(n=g)
__global__ __launch_bounds__(256) void k_finalq(const int* __restrict__ last_node,
                                                float* __restrict__ ws) {
  __shared__ int lL[128];
  int ot = blockIdx.x, gt = blockIdx.y, b = blockIdx.z;
  int t = threadIdx.x, w = t >> 6, lane = t & 63;
  int wr = w >> 1, wc = w & 1, l15 = lane & 15, lk = lane >> 4;
  const unsigned short* wch = (const unsigned short*)(ws + WS_WCH);
  const unsigned short* wcl = (const unsigned short*)(ws + WS_WCL);
  const unsigned short* ph = (const unsigned short*)(ws + WS_PH);
  const unsigned short* pl = (const unsigned short*)(ws + WS_PL2);
  const unsigned short* eh = (const unsigned short*)(ws + WS_EH);
  const unsigned short* el = (const unsigned short*)(ws + WS_EL);
  unsigned short* fh = (unsigned short*)(ws + WS_FH);
  unsigned short* fl = (unsigned short*)(ws + WS_FL);
  if (t < 128) {
    int g = gt*128 + t;
    lL[t] = last_node[b*Gg + (g < Gg ? g : Gg-1)];
  }
  __syncthreads();
  int obase = ot*128 + wr*64;
  int gbase = gt*128 + wc*64;
  f32x4 acc[4][4] = {};
  size_t arow[4], prow[4], lrow[4];
  int gidx[4];
#pragma unroll
  for (int fm = 0; fm < 4; ++fm)
    arow[fm] = ((size_t)(obase + fm*16 + l15)) * 512;
#pragma unroll
  for (int fn = 0; fn < 4; ++fn) {
    gidx[fn] = gbase + fn*16 + l15;
    prow[fn] = ((size_t)(b*GP + gidx[fn])) * Hh;
    lrow[fn] = ((size_t)(b*Nn + lL[wc*64 + fn*16 + l15])) * Hh;
  }
  for (int k0 = 0; k0 < 512; k0 += 32) {
    bf16x8 ahi[4], alo[4], bhi[4], blo[4];
#pragma unroll
    for (int fm = 0; fm < 4; ++fm) {
      ahi[fm] = *(const bf16x8*)(wch + arow[fm] + k0 + lk*8);
      alo[fm] = *(const bf16x8*)(wcl + arow[fm] + k0 + lk*8);
    }
    if (k0 < 256) {
#pragma unroll
      for (int fn = 0; fn < 4; ++fn) {
        bhi[fn] = *(const bf16x8*)(ph + prow[fn] + k0 + lk*8);
        blo[fn] = *(const bf16x8*)(pl + prow[fn] + k0 + lk*8);
      }
    } else {
#pragma unroll
      for (int fn = 0; fn < 4; ++fn) {
        bhi[fn] = *(const bf16x8*)(eh + lrow[fn] + (k0-256) + lk*8);
        blo[fn] = *(const bf16x8*)(el + lrow[fn] + (k0-256) + lk*8);
      }
    }
#pragma unroll
    for (int fm = 0; fm < 4; ++fm)
#pragma unroll
      for (int fn = 0; fn < 4; ++fn) {
        acc[fm][fn] = MFMA(ahi[fm], bhi[fn], acc[fm][fn]);
        acc[fm][fn] = MFMA(ahi[fm], blo[fn], acc[fm][fn]);
        acc[fm][fn] = MFMA(alo[fm], bhi[fn], acc[fm][fn]);
      }
  }
#pragma unroll
  for (int fm = 0; fm < 4; ++fm) {
    int o = obase + fm*16 + lk*4;
    float4 qv = *(const float4*)(ws + WS_QG + b*Hh + o);
    float q4[4] = {qv.x, qv.y, qv.z, qv.w};
#pragma unroll
    for (int fn = 0; fn < 4; ++fn) {
      u16x4 vh, vl;
#pragma unroll
      for (int j = 0; j < 4; ++j) {
        unsigned short hi, lo;
        split1(acc[fm][fn][j] + q4[j], hi, lo);
        vh[j] = hi; vl[j] = lo;
      }
      size_t idx = ((size_t)(b*GP + gidx[fn])) * Hh + o;
      *(u16x4*)(fh + idx) = vh;
      *(u16x4*)(fl + idx) = vl;
    }
  }
}

// ---------------- fused score + softmax + normalize ----------------
// grid(gt=8, b=64), block(512)=8 waves (wr=w>>1 n-quarter, wc=w&1 g-half)
// A=emb(m=n), B=fq(n=g); block owns 64 g-rows x all n; p kept in fp16 LDS.
#define PSTRIDE 1028
__global__ __launch_bounds__(512) void k_score(const float* __restrict__ dists,
                                               const int* __restrict__ last_node,
                                               float* __restrict__ ws,
                                               float* __restrict__ out) {
  __shared__ __align__(8) unsigned short pbuf[64 * PSTRIDE];  // 131584 B
  __shared__ int lL[64];
  __shared__ float rsp[8][32];
  __shared__ float inv[64];
  int gt = blockIdx.x, b = blockIdx.y;
  int t = threadIdx.x, w = t >> 6, lane = t & 63;
  int wr = w >> 1, wc = w & 1, l15 = lane & 15, lk = lane >> 4;
  const unsigned short* eh = (const unsigned short*)(ws + WS_EH);
  const unsigned short* el = (const unsigned short*)(ws + WS_EL);
  const unsigned short* fh = (const unsigned short*)(ws + WS_FH);
  const unsigned short* fl = (const unsigned short*)(ws + WS_FL);
  const unsigned short* bm = (const unsigned short*)(ws + WS_BM);
  if (t < 64) lL[t] = last_node[b*Gg + ((gt*64 + t) < Gg ? (gt*64 + t) : Gg-1)];
  __syncthreads();
  int gl[2];
  size_t frow[2];
#pragma unroll
  for (int fn = 0; fn < 2; ++fn) {
    gl[fn] = wc*32 + fn*16 + l15;
    frow[fn] = ((size_t)(b*GP + gt*64 + gl[fn])) * Hh;
  }
  float rsum[2] = {0.f, 0.f};
  const float c2 = 0.70710678118654752f;
  for (int nt = 0; nt < 8; ++nt) {
    size_t arow[2];
#pragma unroll
    for (int fm = 0; fm < 2; ++fm) {
      int nr = nt*128 + wr*32 + fm*16 + l15;
      if (nr > Nn-1) nr = Nn-1;
      arow[fm] = ((size_t)(b*Nn + nr)) * Hh;
    }
    f32x4 acc[2][2] = {};
    for (int k0 = 0; k0 < 256; k0 += 32) {
      bf16x8 ahi[2], alo[2], bhi[2], blo[2];
#pragma unroll
      for (int fm = 0; fm < 2; ++fm) {
        ahi[fm] = *(const bf16x8*)(eh + arow[fm] + k0 + lk*8);
        alo[fm] = *(const bf16x8*)(el + arow[fm] + k0 + lk*8);
      }
#pragma unroll
      for (int fn = 0; fn < 2; ++fn) {
        bhi[fn] = *(const bf16x8*)(fh + frow[fn] + k0 + lk*8);
        blo[fn] = *(const bf16x8*)(fl + frow[fn] + k0 + lk*8);
      }
#pragma unroll
      for (int fm = 0; fm < 2; ++fm)
#pragma unroll
        for (int fn = 0; fn < 2; ++fn) {
          acc[fm][fn] = MFMA(ahi[fm], bhi[fn], acc[fm][fn]);
          acc[fm][fn] = MFMA(ahi[fm], blo[fn], acc[fm][fn]);
          acc[fm][fn] = MFMA(alo[fm], bhi[fn], acc[fm][fn]);
        }
    }
    // epilogue: 4 consecutive n per (fm,fn)
#pragma unroll
    for (int fm = 0; fm < 2; ++fm) {
      int nb = nt*128 + wr*32 + fm*16 + lk*4;
      if (nb < Nn) {
#pragma unroll
        for (int fn = 0; fn < 2; ++fn) {
          int g = gl[fn];
          int L = lL[g];
          float4 d4 = *(const float4*)(dists + ((size_t)(b*Nn + L)) * Nn + nb);
          unsigned cbits = bm[((size_t)(b*GP + gt*64 + g)) * 64 + (nb >> 4)];
          int bo = nb & 15;
          float dd[4] = {d4.x, d4.y, d4.z, d4.w};
          float pv[4];
          float s = 0.f;
#pragma unroll
          for (int j = 0; j < 4; ++j) {
            float sc = acc[fm][fn][j] * 0.0625f - dd[j] * c2;
            float p = ((cbits >> (bo + j)) & 1) ? 0.f : __expf(tanh10(sc) - 10.0f);
            pv[j] = p; s += p;
          }
          rsum[fn] += s;
          unsigned lo = (unsigned)__half_as_ushort(__float2half(pv[0])) |
                        ((unsigned)__half_as_ushort(__float2half(pv[1])) << 16);
          unsigned hi = (unsigned)__half_as_ushort(__float2half(pv[2])) |
                        ((unsigned)__half_as_ushort(__float2half(pv[3])) << 16);
          uint2 u = {lo, hi};
          *(uint2*)&pbuf[g * PSTRIDE + nb] = u;
        }
      }
    }
  }
  // row-sum reduce: over lk (shfl), then over wr (LDS)
#pragma unroll
  for (int fn = 0; fn < 2; ++fn) {
    rsum[fn] += __shfl_xor(rsum[fn], 16);
    rsum[fn] += __shfl_xor(rsum[fn], 32);
  }
  if (lk == 0) {
    rsp[w][l15] = rsum[0];
    rsp[w][16 + l15] = rsum[1];
  }
  __syncthreads();
  if (t < 64) {
    int wcg = t >> 5, idx = t & 31;
    float s = rsp[0*2 + wcg][idx] + rsp[1*2 + wcg][idx] +
              rsp[2*2 + wcg][idx] + rsp[3*2 + wcg][idx];
    inv[t] = 1.0f / s;
  }
  __syncthreads();
  // normalize + store: 8 threads per g-row, float4 columns
  {
    int r = t >> 3, c0 = t & 7;
    int g = gt*64 + r;
    if (g < Gg) {
      float iv = inv[r];
      float* orow = out + ((size_t)(b*Gg + g)) * Nn;
      for (int f4 = c0; f4 < 250; f4 += 8) {
        uint2 u = *(const uint2*)&pbuf[r * PSTRIDE + f4*4];
        float4 o4;
        o4.x = __half2float(__ushort_as_half((unsigned short)(u.x & 0xFFFF))) * iv;
        o4.y = __half2float(__ushort_as_half((unsigned short)(u.x >> 16))) * iv;
        o4.z = __half2float(__ushort_as_half((unsigned short)(u.y & 0xFFFF))) * iv;
        o4.w = __half2float(__ushort_as_half((unsigned short)(u.y >> 16))) * iv;
        *(float4*)(orow + f4*4) = o4;
      }
    }
  }
}

extern "C" void kernel_launch(void* const* d_in, const int* in_sizes, int n_in,
                              void* d_out, int out_size, void* d_ws, size_t ws_size,
                              hipStream_t stream) {
  const float* emb       = (const float*)d_in[0];
  const float* dists     = (const float*)d_in[1];
  const int*   last_node = (const int*)d_in[2];
  const float* gm        = (const float*)d_in[3];
  const float* Wg        = (const float*)d_in[4];
  const float* Wf        = (const float*)d_in[5];
  const float* Wl        = (const float*)d_in[6];
  const float* Wv        = (const float*)d_in[7];
  float* out = (float*)d_out;
  float* ws  = (float*)d_ws;

  hipLaunchKernelGGL(k_zero,   dim3(64),        dim3(256), 0, stream, ws);
  hipLaunchKernelGGL(k_prep,   dim3(16,4,Bb),   dim3(256), 0, stream, emb, ws);
  hipLaunchKernelGGL(k_qgraph, dim3(Bb),        dim3(256), 0, stream, Wg, ws);
  hipLaunchKernelGGL(k_wcat,   dim3(256),       dim3(256), 0, stream, Wf, Wl, Wv, ws);
  hipLaunchKernelGGL(k_bm,     dim3(Bb*GP/4),   dim3(256), 0, stream, gm, ws);
  hipLaunchKernelGGL(k_pool,   dim3(2,4,Bb),    dim3(256), 0, stream, ws);
  hipLaunchKernelGGL(k_finalq, dim3(2,4,Bb),    dim3(256), 0, stream, last_node, ws);
  hipLaunchKernelGGL(k_score,  dim3(8,Bb),      dim3(512), 0, stream, dists, last_node, ws, out);
}